// Round 6
// baseline (1003.407 us; speedup 1.0000x reference)
//
#include <hip/hip_runtime.h>
#include <cstdint>
#include <cstddef>

// MultiHeadAttention: B=2, N=2048, EMB=2048, H=8, D=256.  fp32 I/O.
// R11: QKV all-DMA (VALU fixed).  R12: attn 391us was barrier/DMA-latency
// bound (MfmaUtil 14, VALU 12, HBM 7.5 -- all idle; 29k cyc/iter vs ~3.5k
// phase sum).  Root cause: single-buffered K -> 2 barriers/iter, each
// draining vmcnt(0) incl. the just-issued next-tile DMA (HBM-latency K).
// Fix: (a) Kh DOUBLE-buffered in LDS (same 64KB) -> ONE barrier/iter, DMA
// issued a full iteration ahead; (b) Kl dropped from LDS, read from global
// in pass 3 with 2-stage register prefetch (like V); (c) V 2-stage register
// prefetch; (d) defer-max: skip o-rescale when alpha==1 exactly (bitwise
// identical).  MFMA order per (j,t) preserved -> same absmax.
// ws (96 MiB): qh 16 | ql 16 | kh 16 | kl 16 | vT 16 | attn 16 ;
// wprojT aliases qh after attention; attn slot = W-split scratch during
// QKV phases, then attention output.

typedef __bf16 bf16x8 __attribute__((ext_vector_type(8)));
typedef __bf16 bf16x2 __attribute__((ext_vector_type(2)));
typedef float f32x4 __attribute__((ext_vector_type(4)));

#define SCALE_INV 0.022097086912079608f  // 1/sqrt(2048)

// Direct global->LDS 16B DMA (per-lane global src, wave-uniform LDS dest).
#define GLDS16(gp, lp)                                                        \
  __builtin_amdgcn_global_load_lds(                                           \
      (const __attribute__((address_space(1))) void*)(gp),                    \
      (__attribute__((address_space(3))) void*)(lp), 16, 0, 0)

__device__ inline void split8(const float4 v0, const float4 v1, bf16x8& hi,
                              bf16x8& lo) {
  float a[8] = {v0.x, v0.y, v0.z, v0.w, v1.x, v1.y, v1.z, v1.w};
  bf16x8 h, l;
#pragma unroll
  for (int i = 0; i < 8; i++) {
    __bf16 hh = (__bf16)a[i];
    h[i] = hh;
    l[i] = (__bf16)(a[i] - (float)hh);
  }
  hi = h;
  lo = l;
}

// X [4096][2048] fp32 -> Xh/Xl bf16 (hi/lo split), same row-major layout.
__global__ __launch_bounds__(256) void presplit_x_k(
    const float* __restrict__ X, __bf16* __restrict__ Xh,
    __bf16* __restrict__ Xl) {
  const size_t i = ((size_t)blockIdx.x * 256 + threadIdx.x) * 8;
  const float4 v0 = *(const float4*)&X[i];
  const float4 v1 = *(const float4*)&X[i + 4];
  bf16x8 h, l;
  split8(v0, v1, h, l);
  *(bf16x8*)&Xh[i] = h;
  *(bf16x8*)&Xl[i] = l;
}

// out[c][r] = (bf16) in[r][c]
__global__ __launch_bounds__(256) void transpose_cvt_k(
    const float* __restrict__ in, __bf16* __restrict__ out, int R, int C) {
  __shared__ float tile[32][33];
  const int tx = threadIdx.x & 31;
  const int ty = threadIdx.x >> 5;
  const int c0 = blockIdx.x * 32;
  const int r0 = blockIdx.y * 32;
#pragma unroll
  for (int i = 0; i < 32; i += 8)
    tile[ty + i][tx] = in[(size_t)(r0 + ty + i) * C + (c0 + tx)];
  __syncthreads();
#pragma unroll
  for (int i = 0; i < 32; i += 8)
    out[(size_t)(c0 + ty + i) * R + (r0 + tx)] = (__bf16)tile[tx][ty + i];
}

// W cols [col0, col0+2048) of [2048][6144] fp32 -> split-bf16 transposed:
// wh[c-col0][r] = hi(W[r][c]), wl[c-col0][r] = lo.  64x64 tiles.
__global__ __launch_bounds__(256) void transpose_w_split_k(
    const float* __restrict__ in, __bf16* __restrict__ wh,
    __bf16* __restrict__ wl, int col0) {
  __shared__ float tile[64][65];
  const int tid = threadIdx.x;
  const int c0 = col0 + blockIdx.x * 64;  // absolute W col
  const int r0 = blockIdx.y * 64;         // W row = out col
  const int cx = tid & 15, ry = tid >> 4;  // load: 16 float4 x 16 rows
#pragma unroll
  for (int p = 0; p < 4; p++) {
    const float4 v =
        *(const float4*)&in[(size_t)(r0 + p * 16 + ry) * 6144 + c0 + cx * 4];
    tile[p * 16 + ry][cx * 4 + 0] = v.x;
    tile[p * 16 + ry][cx * 4 + 1] = v.y;
    tile[p * 16 + ry][cx * 4 + 2] = v.z;
    tile[p * 16 + ry][cx * 4 + 3] = v.w;
  }
  __syncthreads();
  const int r2 = tid & 31;  // r-pair index
  const int cy = tid >> 5;  // 0..7
  const int cbase = c0 - col0;
#pragma unroll
  for (int p = 0; p < 8; p++) {
    const int cl = cy + p * 8;
    const float t0 = tile[2 * r2][cl];
    const float t1 = tile[2 * r2 + 1][cl];
    const __bf16 h0 = (__bf16)t0, h1 = (__bf16)t1;
    bf16x2 hv = {h0, h1};
    bf16x2 lv = {(__bf16)(t0 - (float)h0), (__bf16)(t1 - (float)h1)};
    *(bf16x2*)&wh[(size_t)(cbase + cl) * 2048 + r0 + 2 * r2] = hv;
    *(bf16x2*)&wl[(size_t)(cbase + cl) * 2048 + r0 + 2 * r2] = lv;
  }
}

// QKV GEMM phase (2048 output cols), split-bf16 3-pass, ALL-DMA staging.
__global__ __launch_bounds__(256) void gemm_qkv_dma_k(
    const __bf16* __restrict__ Xh, const __bf16* __restrict__ Xl,
    const __bf16* __restrict__ Wh, const __bf16* __restrict__ Wl,
    const float* __restrict__ bias, int nbase, __bf16* __restrict__ qh_,
    __bf16* __restrict__ ql_, __bf16* __restrict__ kh_,
    __bf16* __restrict__ kl_, __bf16* __restrict__ vT) {
  __shared__ __attribute__((aligned(16))) __bf16 AhL[2][4096];  // 16 KB
  __shared__ __attribute__((aligned(16))) __bf16 AlL[2][4096];  // 16 KB
  __shared__ __attribute__((aligned(16))) __bf16 BhL[2][4096];  // 16 KB
  __shared__ __attribute__((aligned(16))) __bf16 BlL[2][4096];  // 16 KB
  const int tid = threadIdx.x, lane = tid & 63, wave = tid >> 6;
  const int l16 = lane & 15, quad = lane >> 4;
  const int wm = (wave >> 1) * 64, wn = (wave & 1) * 64;
  const int m0 = blockIdx.y * 128, n0 = blockIdx.x * 128;

  f32x4 zero4 = {0.f, 0.f, 0.f, 0.f};
  f32x4 acc[4][4];
#pragma unroll
  for (int i = 0; i < 4; i++)
#pragma unroll
    for (int j = 0; j < 4; j++) acc[i][j] = zero4;

  const int rowl = lane >> 2, gq = lane & 3;
  const int sg = gq ^ (rowl & 3);
  size_t srcOff[2];
  int dst[2];
#pragma unroll
  for (int i = 0; i < 2; i++) {
    const int row = wave * 32 + i * 16 + rowl;
    srcOff[i] = (size_t)row * 2048 + sg * 8;
    dst[i] = (wave * 32 + i * 16) * 32;
  }
  const __bf16* AhG = Xh + (size_t)m0 * 2048;
  const __bf16* AlG = Xl + (size_t)m0 * 2048;
  const __bf16* BhG = Wh + (size_t)n0 * 2048;
  const __bf16* BlG = Wl + (size_t)n0 * 2048;

  const int aro = (wm + l16) * 32 + ((quad ^ (l16 & 3)) << 3);
  const int bro = (wn + l16) * 32 + ((quad ^ (l16 & 3)) << 3);

#define STAGEQ(buf, koff)                                                     \
  do {                                                                        \
    GLDS16(AhG + srcOff[0] + (koff), &AhL[buf][dst[0]]);                      \
    GLDS16(AhG + srcOff[1] + (koff), &AhL[buf][dst[1]]);                      \
    GLDS16(AlG + srcOff[0] + (koff), &AlL[buf][dst[0]]);                      \
    GLDS16(AlG + srcOff[1] + (koff), &AlL[buf][dst[1]]);                      \
    GLDS16(BhG + srcOff[0] + (koff), &BhL[buf][dst[0]]);                      \
    GLDS16(BhG + srcOff[1] + (koff), &BhL[buf][dst[1]]);                      \
    GLDS16(BlG + srcOff[0] + (koff), &BlL[buf][dst[0]]);                      \
    GLDS16(BlG + srcOff[1] + (koff), &BlL[buf][dst[1]]);                      \
  } while (0)

  STAGEQ(0, 0);

  for (int k0 = 0; k0 < 2048; k0 += 32) {
    const int cur = (k0 >> 5) & 1;
    __syncthreads();
    const int nxt = k0 + 32;
    if (nxt < 2048) STAGEQ(cur ^ 1, nxt);
    bf16x8 fah[4], fal[4], fbh[4], fbl[4];
#pragma unroll
    for (int i = 0; i < 4; i++) {
      fah[i] = *(const bf16x8*)&AhL[cur][aro + i * 512];
      fal[i] = *(const bf16x8*)&AlL[cur][aro + i * 512];
    }
#pragma unroll
    for (int j = 0; j < 4; j++) {
      fbh[j] = *(const bf16x8*)&BhL[cur][bro + j * 512];
      fbl[j] = *(const bf16x8*)&BlL[cur][bro + j * 512];
    }
#pragma unroll
    for (int i = 0; i < 4; i++)
#pragma unroll
      for (int j = 0; j < 4; j++) {
        acc[i][j] = __builtin_amdgcn_mfma_f32_16x16x32_bf16(fah[i], fbh[j],
                                                            acc[i][j], 0, 0, 0);
        acc[i][j] = __builtin_amdgcn_mfma_f32_16x16x32_bf16(fah[i], fbl[j],
                                                            acc[i][j], 0, 0, 0);
        acc[i][j] = __builtin_amdgcn_mfma_f32_16x16x32_bf16(fal[i], fbh[j],
                                                            acc[i][j], 0, 0, 0);
      }
  }
#undef STAGEQ

#pragma unroll
  for (int i = 0; i < 4; i++) {
#pragma unroll
    for (int j = 0; j < 4; j++) {
      const int col = nbase + n0 + wn + j * 16 + l16;
      const float bv = bias[col];
      const int h = col / 768;
      const int rr = col - h * 768;
      const int d = rr / 3;
      const int c = rr - d * 3;
#pragma unroll
      for (int r = 0; r < 4; r++) {
        const int row = m0 + wm + i * 16 + quad * 4 + r;
        const float v = acc[i][j][r] + bv;
        const int b = row >> 11;
        const int nn = row & 2047;
        const int bh = b * 8 + h;
        const size_t idx = ((size_t)bh * 2048 + nn) * 256 + d;
        if (c == 0) {
          __bf16 hi = (__bf16)v;
          qh_[idx] = hi;
          ql_[idx] = (__bf16)(v - (float)hi);
        } else if (c == 1) {
          __bf16 hi = (__bf16)v;
          kh_[idx] = hi;
          kl_[idx] = (__bf16)(v - (float)hi);
        } else {
          vT[((size_t)bh * 256 + d) * 2048 + nn] = (__bf16)v;
        }
      }
    }
  }
}

// Flash attention, kv-tile 64.  Q hi/lo in registers; Kh DOUBLE-buffered in
// LDS (XOR-swizzled DMA, one barrier per iter, DMA issued a full iter ahead
// of its consuming barrier); Kl and V read from global (L2-resident) with
// 2-stage register prefetch; defer-max skips the exact-alpha==1 rescale.
__global__ __launch_bounds__(256, 2) void attn_fwd_k(
    const __bf16* __restrict__ Qh,  // [16][2048][256]
    const __bf16* __restrict__ Ql,
    const __bf16* __restrict__ Kh,
    const __bf16* __restrict__ Kl,
    const __bf16* __restrict__ Vt,  // [16][256][2048]
    __bf16* __restrict__ out) {     // [2][2048][2048] (b, n, h*256+d)
  __shared__ __attribute__((aligned(16))) __bf16 KhL[2][64 * 256];  // 64 KB
  __shared__ __attribute__((aligned(16))) __bf16 Plds[4][16 * 72];  // 9 KB

  const int qblk = blockIdx.x;
  const int bh = blockIdx.y;
  const int bb = bh >> 3, hh = bh & 7;
  const int tid = threadIdx.x, lane = tid & 63, wave = tid >> 6;
  const int l16 = lane & 15, quad = lane >> 4;

  const size_t hqk = (size_t)bh * 2048 * 256;
  const __bf16* qhp = Qh + hqk;
  const __bf16* qlp = Ql + hqk;
  const __bf16* khp = Kh + hqk;
  const __bf16* klp = Kl + hqk;
  const __bf16* vp = Vt + (size_t)bh * 256 * 2048;

  const int qrow = qblk * 64 + wave * 16;

  bf16x8 qhf[8], qlf[8];
#pragma unroll
  for (int t = 0; t < 8; t++) {
    const size_t off = (size_t)(qrow + l16) * 256 + t * 32 + quad * 8;
    qhf[t] = *(const bf16x8*)&qhp[off];
    qlf[t] = *(const bf16x8*)&qlp[off];
  }

  f32x4 zero4 = {0.f, 0.f, 0.f, 0.f};
  f32x4 o[16];
#pragma unroll
  for (int dt = 0; dt < 16; dt++) o[dt] = zero4;
  float mrow[4], lrow[4];
#pragma unroll
  for (int r = 0; r < 4; r++) {
    mrow[r] = -3.0e38f;
    lrow[r] = 0.f;
  }

  // Kh staging: wave w stages tile rows [w*16, w*16+16); instr i covers 2
  // rows.  Source pre-swizzled (16B granule ^ (row&7)) so linear LDS dest
  // yields swizzled layout; reads apply the same XOR.
  int koff[8];
#pragma unroll
  for (int i = 0; i < 8; i++) {
    const int r = wave * 16 + i * 2 + (lane >> 5);
    const int cb = ((lane & 31) << 4) ^ ((r & 7) << 4);
    koff[i] = r * 256 + (cb >> 1);
  }
  const int ldsb = wave * 4096;  // elems within one buffer

  // prologue: stage tile 0 into buffer 0
#pragma unroll
  for (int i = 0; i < 8; i++) GLDS16(khp + koff[i], &KhL[0][ldsb + i * 512]);

  for (int kv0 = 0; kv0 < 2048; kv0 += 64) {
    const int cur = (kv0 >> 6) & 1;
    __syncthreads();  // buf[cur] DMA drained; buf[cur^1] readers done

    // issue next tile's DMA immediately: a full iteration to land
    if (kv0 + 64 < 2048) {
      const int kvn = (kv0 + 64) * 256;
#pragma unroll
      for (int i = 0; i < 8; i++)
        GLDS16(khp + kvn + koff[i], &KhL[cur ^ 1][ldsb + i * 512]);
    }

    // S = q @ k^T: 4 subtiles, 3-pass.  Kh from LDS, Kl from global with
    // 2-stage register prefetch (j+1 loads issue during j's MFMAs).
    f32x4 s[4];
#pragma unroll
    for (int j = 0; j < 4; j++) s[j] = zero4;
    bf16x8 kq[2][8];
    {
      const __bf16* kr = klp + (size_t)(kv0 + l16) * 256 + quad * 8;
#pragma unroll
      for (int t = 0; t < 8; t++) kq[0][t] = *(const bf16x8*)(kr + t * 32);
    }
    __builtin_amdgcn_s_setprio(1);
#pragma unroll
    for (int j = 0; j < 4; j++) {
      if (j < 3) {
        const __bf16* kr =
            klp + (size_t)(kv0 + (j + 1) * 16 + l16) * 256 + quad * 8;
#pragma unroll
        for (int t = 0; t < 8; t++)
          kq[(j + 1) & 1][t] = *(const bf16x8*)(kr + t * 32);
      }
      const int row = j * 16 + l16;
      const int swz = (row & 7) << 3;
      const int rb = row * 256;
#pragma unroll
      for (int t = 0; t < 8; t++) {
        const int off = rb + ((t * 32 + quad * 8) ^ swz);
        bf16x8 khf = *(const bf16x8*)&KhL[cur][off];
        s[j] =
            __builtin_amdgcn_mfma_f32_16x16x32_bf16(qhf[t], khf, s[j], 0, 0, 0);
        s[j] = __builtin_amdgcn_mfma_f32_16x16x32_bf16(qhf[t], kq[j & 1][t],
                                                       s[j], 0, 0, 0);
        s[j] =
            __builtin_amdgcn_mfma_f32_16x16x32_bf16(qlf[t], khf, s[j], 0, 0, 0);
      }
    }
    __builtin_amdgcn_s_setprio(0);

    // online softmax (rows quad*4+r, cols l16 of 4 kv subtiles)
    float mnew[4], psum[4];
#pragma unroll
    for (int r = 0; r < 4; r++) {
      float mx = fmaxf(fmaxf(s[0][r], s[1][r]), fmaxf(s[2][r], s[3][r]));
#pragma unroll
      for (int off = 1; off < 16; off <<= 1)
        mx = fmaxf(mx, __shfl_xor(mx, off, 16));
      mnew[r] = fmaxf(mrow[r], mx);
      psum[r] = 0.f;
    }
#pragma unroll
    for (int j = 0; j < 4; j++)
#pragma unroll
      for (int r = 0; r < 4; r++) {
        float p = __expf(s[j][r] - mnew[r]);
        s[j][r] = p;
        psum[r] += p;
      }
#pragma unroll
    for (int r = 0; r < 4; r++) {
#pragma unroll
      for (int off = 1; off < 16; off <<= 1)
        psum[r] += __shfl_xor(psum[r], off, 16);
    }
    // defer-max: if no row's max grew, alpha==1 exactly -> skip rescale
    float grow = fmaxf(fmaxf(mnew[0] - mrow[0], mnew[1] - mrow[1]),
                       fmaxf(mnew[2] - mrow[2], mnew[3] - mrow[3]));
    if (__any(grow > 0.f)) {
      float alpha[4];
#pragma unroll
      for (int r = 0; r < 4; r++) {
        alpha[r] = __expf(mrow[r] - mnew[r]);
        lrow[r] = lrow[r] * alpha[r] + psum[r];
        mrow[r] = mnew[r];
      }
#pragma unroll
      for (int dt = 0; dt < 16; dt++) {
        o[dt][0] *= alpha[0];
        o[dt][1] *= alpha[1];
        o[dt][2] *= alpha[2];
        o[dt][3] *= alpha[3];
      }
    } else {
#pragma unroll
      for (int r = 0; r < 4; r++) lrow[r] += psum[r];
    }

    // P: C-layout -> per-wave LDS -> A-operand layout (wave-private)
#pragma unroll
    for (int j = 0; j < 4; j++)
#pragma unroll
      for (int r = 0; r < 4; r++)
        Plds[wave][(quad * 4 + r) * 72 + j * 16 + l16] = (__bf16)s[j][r];
    bf16x8 pa0 = *(const bf16x8*)&Plds[wave][l16 * 72 + quad * 8];
    bf16x8 pa1 = *(const bf16x8*)&Plds[wave][l16 * 72 + 32 + quad * 8];

    // O += P @ V, V from global with 2-stage register prefetch
    const __bf16* vb0 = vp + kv0 + quad * 8;
    bf16x8 vfa[2], vfb[2];
    {
      const __bf16* vr = vb0 + (size_t)l16 * 2048;
      vfa[0] = *(const bf16x8*)vr;
      vfb[0] = *(const bf16x8*)(vr + 32);
    }
    __builtin_amdgcn_s_setprio(1);
#pragma unroll
    for (int dt = 0; dt < 16; dt++) {
      if (dt < 15) {
        const __bf16* vr = vb0 + (size_t)((dt + 1) * 16 + l16) * 2048;
        vfa[(dt + 1) & 1] = *(const bf16x8*)vr;
        vfb[(dt + 1) & 1] = *(const bf16x8*)(vr + 32);
      }
      o[dt] = __builtin_amdgcn_mfma_f32_16x16x32_bf16(pa0, vfa[dt & 1], o[dt],
                                                      0, 0, 0);
      o[dt] = __builtin_amdgcn_mfma_f32_16x16x32_bf16(pa1, vfb[dt & 1], o[dt],
                                                      0, 0, 0);
    }
    __builtin_amdgcn_s_setprio(0);
  }

#pragma unroll
  for (int r = 0; r < 4; r++) {
    const float inv = SCALE_INV / lrow[r];
    const int n = qrow + quad * 4 + r;
    const size_t base = ((size_t)bb * 2048 + n) * 2048 + hh * 256;
#pragma unroll
    for (int dt = 0; dt < 16; dt++)
      out[base + dt * 16 + l16] = (__bf16)(o[dt][r] * inv);
  }
}

// Plain bf16 GEMM, C = A[M][K] * Bt[N][K]^T + bias, fp32 store.
__global__ __launch_bounds__(256) void gemm_bt_k(
    const __bf16* __restrict__ A, const __bf16* __restrict__ Bt,
    const float* __restrict__ bias, int M, int Ncols, int K,
    float* __restrict__ outF) {
  __shared__ __bf16 As[128 * 40];
  __shared__ __bf16 Bs[128 * 40];
  const int tid = threadIdx.x, lane = tid & 63, wave = tid >> 6;
  const int l16 = lane & 15, quad = lane >> 4;
  const int wm = (wave >> 1) * 64, wn = (wave & 1) * 64;
  const int m0 = blockIdx.y * 128, n0 = blockIdx.x * 128;
  const int r0 = tid >> 2, kc0 = (tid & 3) * 8;

  f32x4 zero4 = {0.f, 0.f, 0.f, 0.f};
  f32x4 acc[4][4];
#pragma unroll
  for (int i = 0; i < 4; i++)
#pragma unroll
    for (int j = 0; j < 4; j++) acc[i][j] = zero4;

  const __bf16* Aptr = A + (size_t)(m0 + r0) * K + kc0;
  const __bf16* Bptr = Bt + (size_t)(n0 + r0) * K + kc0;
  const size_t rowstep = (size_t)64 * K;

  for (int k0 = 0; k0 < K; k0 += 32) {
    uint4 a0 = *(const uint4*)(Aptr + k0);
    uint4 a1 = *(const uint4*)(Aptr + rowstep + k0);
    uint4 b0 = *(const uint4*)(Bptr + k0);
    uint4 b1 = *(const uint4*)(Bptr + rowstep + k0);
    __syncthreads();
    *(uint4*)&As[r0 * 40 + kc0] = a0;
    *(uint4*)&As[(r0 + 64) * 40 + kc0] = a1;
    *(uint4*)&Bs[r0 * 40 + kc0] = b0;
    *(uint4*)&Bs[(r0 + 64) * 40 + kc0] = b1;
    __syncthreads();
    bf16x8 af[4], bfv[4];
#pragma unroll
    for (int i = 0; i < 4; i++)
      af[i] = *(const bf16x8*)&As[(wm + i * 16 + l16) * 40 + quad * 8];
#pragma unroll
    for (int j = 0; j < 4; j++)
      bfv[j] = *(const bf16x8*)&Bs[(wn + j * 16 + l16) * 40 + quad * 8];
#pragma unroll
    for (int i = 0; i < 4; i++)
#pragma unroll
      for (int j = 0; j < 4; j++)
        acc[i][j] = __builtin_amdgcn_mfma_f32_16x16x32_bf16(af[i], bfv[j],
                                                            acc[i][j], 0, 0, 0);
  }

#pragma unroll
  for (int i = 0; i < 4; i++)
#pragma unroll
    for (int j = 0; j < 4; j++) {
      const int col = n0 + wn + j * 16 + l16;
      const float bv = bias[col];
#pragma unroll
      for (int r = 0; r < 4; r++) {
        const int row = m0 + wm + i * 16 + quad * 4 + r;
        outF[(size_t)row * Ncols + col] = acc[i][j][r] + bv;
      }
    }
}

extern "C" void kernel_launch(void* const* d_in, const int* in_sizes, int n_in,
                              void* d_out, int out_size, void* d_ws,
                              size_t ws_size, hipStream_t stream) {
  const float* x = (const float*)d_in[0];       // [2,2048,2048]
  const float* w_qkv = (const float*)d_in[1];   // [2048,6144]
  const float* b_qkv = (const float*)d_in[2];   // [6144]
  const float* w_proj = (const float*)d_in[3];  // [2048,2048]
  const float* b_proj = (const float*)d_in[4];  // [2048]
  float* out = (float*)d_out;                   // [2,2048,2048] fp32

  const size_t HSZ = (size_t)16 * 2048 * 256;  // 8M elems = 16 MiB bf16
  __bf16* qh = (__bf16*)d_ws;
  __bf16* ql = qh + HSZ;
  __bf16* kh = ql + HSZ;
  __bf16* kl = kh + HSZ;
  __bf16* vT = kl + HSZ;
  __bf16* attn = vT + HSZ;
  __bf16* wprojT = qh;  // aliases qh/ql region AFTER attention

  // Scratch (exact fits): Xh+Xl = 33.55 MB = d_out; per-phase Wh/Wl =
  // 16.78 MB = attn slot.  d_out dead until gemm_bt_k; attn slot dead
  // until attn_fwd_k.
  __bf16* xh = (__bf16*)out;
  __bf16* xl = xh + (size_t)4096 * 2048;
  __bf16* wsp_h = attn;
  __bf16* wsp_l = wsp_h + (size_t)2048 * 2048;

  presplit_x_k<<<dim3(4096), 256, 0, stream>>>(x, xh, xl);
  for (int ph = 0; ph < 3; ph++) {
    transpose_w_split_k<<<dim3(32, 32), 256, 0, stream>>>(w_qkv, wsp_h, wsp_l,
                                                          ph * 2048);
    gemm_qkv_dma_k<<<dim3(16, 32), 256, 0, stream>>>(
        xh, xl, wsp_h, wsp_l, b_qkv, ph * 2048, qh, ql, kh, kl, vT);
  }
  attn_fwd_k<<<dim3(32, 16), 256, 0, stream>>>(qh, ql, kh, kl, vT, attn);
  transpose_cvt_k<<<dim3(64, 64), 256, 0, stream>>>(w_proj, wprojT, 2048, 2048);
  gemm_bt_k<<<dim3(16, 32), 256, 0, stream>>>(attn, wprojT, b_proj, 4096, 2048,
                                              2048, out);
}

// Round 7
// 872.615 us; speedup vs baseline: 1.1499x; 1.1499x over previous
//
#include <hip/hip_runtime.h>
#include <cstdint>
#include <cstddef>

// MultiHeadAttention: B=2, N=2048, EMB=2048, H=8, D=256.  fp32 I/O.
// R12 post-mortem: Kl-from-global regressed attn 391->509 (16-row x 64B
// gather, ~120cyc MFMA cover vs 200+cyc latency; manual 2-deep prefetch
// over-constrained the scheduler).  R13: revert math path to R11 (Kh+Kl in
// LDS, JIT V loads, 3-pass); change ONLY topology to the m214-verified
// shape: ONE 512-thread block (8 waves) per CU, 128 q-rows/block, Kh+Kl
// DOUBLE-buffered (128KB + 18KB P = 146KB LDS), ONE barrier per kv64 iter,
// DMA issued at iter top -> full-iteration cover, no WAR barrier.  8 waves
// share each K tile (L2 traffic halved), 32 barriers total (was 64).
// ws (96 MiB): qh 16 | ql 16 | kh 16 | kl 16 | vT 16 | attn 16 ;
// wprojT aliases qh after attention; attn slot = W-split scratch during
// QKV phases, then attention output.

typedef __bf16 bf16x8 __attribute__((ext_vector_type(8)));
typedef __bf16 bf16x2 __attribute__((ext_vector_type(2)));
typedef float f32x4 __attribute__((ext_vector_type(4)));

#define SCALE_INV 0.022097086912079608f  // 1/sqrt(2048)

// Direct global->LDS 16B DMA (per-lane global src, wave-uniform LDS dest).
#define GLDS16(gp, lp)                                                        \
  __builtin_amdgcn_global_load_lds(                                           \
      (const __attribute__((address_space(1))) void*)(gp),                    \
      (__attribute__((address_space(3))) void*)(lp), 16, 0, 0)

__device__ inline void split8(const float4 v0, const float4 v1, bf16x8& hi,
                              bf16x8& lo) {
  float a[8] = {v0.x, v0.y, v0.z, v0.w, v1.x, v1.y, v1.z, v1.w};
  bf16x8 h, l;
#pragma unroll
  for (int i = 0; i < 8; i++) {
    __bf16 hh = (__bf16)a[i];
    h[i] = hh;
    l[i] = (__bf16)(a[i] - (float)hh);
  }
  hi = h;
  lo = l;
}

// X [4096][2048] fp32 -> Xh/Xl bf16 (hi/lo split), same row-major layout.
__global__ __launch_bounds__(256) void presplit_x_k(
    const float* __restrict__ X, __bf16* __restrict__ Xh,
    __bf16* __restrict__ Xl) {
  const size_t i = ((size_t)blockIdx.x * 256 + threadIdx.x) * 8;
  const float4 v0 = *(const float4*)&X[i];
  const float4 v1 = *(const float4*)&X[i + 4];
  bf16x8 h, l;
  split8(v0, v1, h, l);
  *(bf16x8*)&Xh[i] = h;
  *(bf16x8*)&Xl[i] = l;
}

// out[c][r] = (bf16) in[r][c]
__global__ __launch_bounds__(256) void transpose_cvt_k(
    const float* __restrict__ in, __bf16* __restrict__ out, int R, int C) {
  __shared__ float tile[32][33];
  const int tx = threadIdx.x & 31;
  const int ty = threadIdx.x >> 5;
  const int c0 = blockIdx.x * 32;
  const int r0 = blockIdx.y * 32;
#pragma unroll
  for (int i = 0; i < 32; i += 8)
    tile[ty + i][tx] = in[(size_t)(r0 + ty + i) * C + (c0 + tx)];
  __syncthreads();
#pragma unroll
  for (int i = 0; i < 32; i += 8)
    out[(size_t)(c0 + ty + i) * R + (r0 + tx)] = (__bf16)tile[tx][ty + i];
}

// W cols [col0, col0+2048) of [2048][6144] fp32 -> split-bf16 transposed:
// wh[c-col0][r] = hi(W[r][c]), wl[c-col0][r] = lo.  64x64 tiles.
__global__ __launch_bounds__(256) void transpose_w_split_k(
    const float* __restrict__ in, __bf16* __restrict__ wh,
    __bf16* __restrict__ wl, int col0) {
  __shared__ float tile[64][65];
  const int tid = threadIdx.x;
  const int c0 = col0 + blockIdx.x * 64;  // absolute W col
  const int r0 = blockIdx.y * 64;         // W row = out col
  const int cx = tid & 15, ry = tid >> 4;  // load: 16 float4 x 16 rows
#pragma unroll
  for (int p = 0; p < 4; p++) {
    const float4 v =
        *(const float4*)&in[(size_t)(r0 + p * 16 + ry) * 6144 + c0 + cx * 4];
    tile[p * 16 + ry][cx * 4 + 0] = v.x;
    tile[p * 16 + ry][cx * 4 + 1] = v.y;
    tile[p * 16 + ry][cx * 4 + 2] = v.z;
    tile[p * 16 + ry][cx * 4 + 3] = v.w;
  }
  __syncthreads();
  const int r2 = tid & 31;  // r-pair index
  const int cy = tid >> 5;  // 0..7
  const int cbase = c0 - col0;
#pragma unroll
  for (int p = 0; p < 8; p++) {
    const int cl = cy + p * 8;
    const float t0 = tile[2 * r2][cl];
    const float t1 = tile[2 * r2 + 1][cl];
    const __bf16 h0 = (__bf16)t0, h1 = (__bf16)t1;
    bf16x2 hv = {h0, h1};
    bf16x2 lv = {(__bf16)(t0 - (float)h0), (__bf16)(t1 - (float)h1)};
    *(bf16x2*)&wh[(size_t)(cbase + cl) * 2048 + r0 + 2 * r2] = hv;
    *(bf16x2*)&wl[(size_t)(cbase + cl) * 2048 + r0 + 2 * r2] = lv;
  }
}

// QKV GEMM phase (2048 output cols), split-bf16 3-pass, ALL-DMA staging.
__global__ __launch_bounds__(256) void gemm_qkv_dma_k(
    const __bf16* __restrict__ Xh, const __bf16* __restrict__ Xl,
    const __bf16* __restrict__ Wh, const __bf16* __restrict__ Wl,
    const float* __restrict__ bias, int nbase, __bf16* __restrict__ qh_,
    __bf16* __restrict__ ql_, __bf16* __restrict__ kh_,
    __bf16* __restrict__ kl_, __bf16* __restrict__ vT) {
  __shared__ __attribute__((aligned(16))) __bf16 AhL[2][4096];  // 16 KB
  __shared__ __attribute__((aligned(16))) __bf16 AlL[2][4096];  // 16 KB
  __shared__ __attribute__((aligned(16))) __bf16 BhL[2][4096];  // 16 KB
  __shared__ __attribute__((aligned(16))) __bf16 BlL[2][4096];  // 16 KB
  const int tid = threadIdx.x, lane = tid & 63, wave = tid >> 6;
  const int l16 = lane & 15, quad = lane >> 4;
  const int wm = (wave >> 1) * 64, wn = (wave & 1) * 64;
  const int m0 = blockIdx.y * 128, n0 = blockIdx.x * 128;

  f32x4 zero4 = {0.f, 0.f, 0.f, 0.f};
  f32x4 acc[4][4];
#pragma unroll
  for (int i = 0; i < 4; i++)
#pragma unroll
    for (int j = 0; j < 4; j++) acc[i][j] = zero4;

  const int rowl = lane >> 2, gq = lane & 3;
  const int sg = gq ^ (rowl & 3);
  size_t srcOff[2];
  int dst[2];
#pragma unroll
  for (int i = 0; i < 2; i++) {
    const int row = wave * 32 + i * 16 + rowl;
    srcOff[i] = (size_t)row * 2048 + sg * 8;
    dst[i] = (wave * 32 + i * 16) * 32;
  }
  const __bf16* AhG = Xh + (size_t)m0 * 2048;
  const __bf16* AlG = Xl + (size_t)m0 * 2048;
  const __bf16* BhG = Wh + (size_t)n0 * 2048;
  const __bf16* BlG = Wl + (size_t)n0 * 2048;

  const int aro = (wm + l16) * 32 + ((quad ^ (l16 & 3)) << 3);
  const int bro = (wn + l16) * 32 + ((quad ^ (l16 & 3)) << 3);

#define STAGEQ(buf, koff)                                                     \
  do {                                                                        \
    GLDS16(AhG + srcOff[0] + (koff), &AhL[buf][dst[0]]);                      \
    GLDS16(AhG + srcOff[1] + (koff), &AhL[buf][dst[1]]);                      \
    GLDS16(AlG + srcOff[0] + (koff), &AlL[buf][dst[0]]);                      \
    GLDS16(AlG + srcOff[1] + (koff), &AlL[buf][dst[1]]);                      \
    GLDS16(BhG + srcOff[0] + (koff), &BhL[buf][dst[0]]);                      \
    GLDS16(BhG + srcOff[1] + (koff), &BhL[buf][dst[1]]);                      \
    GLDS16(BlG + srcOff[0] + (koff), &BlL[buf][dst[0]]);                      \
    GLDS16(BlG + srcOff[1] + (koff), &BlL[buf][dst[1]]);                      \
  } while (0)

  STAGEQ(0, 0);

  for (int k0 = 0; k0 < 2048; k0 += 32) {
    const int cur = (k0 >> 5) & 1;
    __syncthreads();
    const int nxt = k0 + 32;
    if (nxt < 2048) STAGEQ(cur ^ 1, nxt);
    bf16x8 fah[4], fal[4], fbh[4], fbl[4];
#pragma unroll
    for (int i = 0; i < 4; i++) {
      fah[i] = *(const bf16x8*)&AhL[cur][aro + i * 512];
      fal[i] = *(const bf16x8*)&AlL[cur][aro + i * 512];
    }
#pragma unroll
    for (int j = 0; j < 4; j++) {
      fbh[j] = *(const bf16x8*)&BhL[cur][bro + j * 512];
      fbl[j] = *(const bf16x8*)&BlL[cur][bro + j * 512];
    }
#pragma unroll
    for (int i = 0; i < 4; i++)
#pragma unroll
      for (int j = 0; j < 4; j++) {
        acc[i][j] = __builtin_amdgcn_mfma_f32_16x16x32_bf16(fah[i], fbh[j],
                                                            acc[i][j], 0, 0, 0);
        acc[i][j] = __builtin_amdgcn_mfma_f32_16x16x32_bf16(fah[i], fbl[j],
                                                            acc[i][j], 0, 0, 0);
        acc[i][j] = __builtin_amdgcn_mfma_f32_16x16x32_bf16(fal[i], fbh[j],
                                                            acc[i][j], 0, 0, 0);
      }
  }
#undef STAGEQ

#pragma unroll
  for (int i = 0; i < 4; i++) {
#pragma unroll
    for (int j = 0; j < 4; j++) {
      const int col = nbase + n0 + wn + j * 16 + l16;
      const float bv = bias[col];
      const int h = col / 768;
      const int rr = col - h * 768;
      const int d = rr / 3;
      const int c = rr - d * 3;
#pragma unroll
      for (int r = 0; r < 4; r++) {
        const int row = m0 + wm + i * 16 + quad * 4 + r;
        const float v = acc[i][j][r] + bv;
        const int b = row >> 11;
        const int nn = row & 2047;
        const int bh = b * 8 + h;
        const size_t idx = ((size_t)bh * 2048 + nn) * 256 + d;
        if (c == 0) {
          __bf16 hi = (__bf16)v;
          qh_[idx] = hi;
          ql_[idx] = (__bf16)(v - (float)hi);
        } else if (c == 1) {
          __bf16 hi = (__bf16)v;
          kh_[idx] = hi;
          kl_[idx] = (__bf16)(v - (float)hi);
        } else {
          vT[((size_t)bh * 256 + d) * 2048 + nn] = (__bf16)v;
        }
      }
    }
  }
}

// Flash attention, kv-tile 64, m214 topology: ONE 512-thread block (8 waves)
// per CU, 128 q-rows/block (16/wave).  Kh+Kl DOUBLE-buffered in LDS
// (XOR-swizzled DMA staging, 8 waves share each tile), ONE barrier per iter,
// DMA issued at iter top -> full-iteration cover.  V read JIT from global
// (L2-resident, compiler-scheduled).  Math path identical to R11.
__global__ __launch_bounds__(512, 1) void attn_fwd_k(
    const __bf16* __restrict__ Qh,  // [16][2048][256]
    const __bf16* __restrict__ Ql,
    const __bf16* __restrict__ Kh,
    const __bf16* __restrict__ Kl,
    const __bf16* __restrict__ Vt,  // [16][256][2048]
    __bf16* __restrict__ out) {     // [2][2048][2048] (b, n, h*256+d)
  __shared__ __attribute__((aligned(16))) __bf16 KhL[2][64 * 256];  // 64 KB
  __shared__ __attribute__((aligned(16))) __bf16 KlL[2][64 * 256];  // 64 KB
  __shared__ __attribute__((aligned(16))) __bf16 Plds[8][16 * 72];  // 18 KB

  const int qblk = blockIdx.x;
  const int bh = blockIdx.y;
  const int bb = bh >> 3, hh = bh & 7;
  const int tid = threadIdx.x, lane = tid & 63, wave = tid >> 6;
  const int l16 = lane & 15, quad = lane >> 4;

  const size_t hqk = (size_t)bh * 2048 * 256;
  const __bf16* qhp = Qh + hqk;
  const __bf16* qlp = Ql + hqk;
  const __bf16* khp = Kh + hqk;
  const __bf16* klp = Kl + hqk;
  const __bf16* vp = Vt + (size_t)bh * 256 * 2048;

  const int qrow = qblk * 128 + wave * 16;

  bf16x8 qhf[8], qlf[8];
#pragma unroll
  for (int t = 0; t < 8; t++) {
    const size_t off = (size_t)(qrow + l16) * 256 + t * 32 + quad * 8;
    qhf[t] = *(const bf16x8*)&qhp[off];
    qlf[t] = *(const bf16x8*)&qlp[off];
  }

  f32x4 zero4 = {0.f, 0.f, 0.f, 0.f};
  f32x4 o[16];
#pragma unroll
  for (int dt = 0; dt < 16; dt++) o[dt] = zero4;
  float mrow[4], lrow[4];
#pragma unroll
  for (int r = 0; r < 4; r++) {
    mrow[r] = -3.0e38f;
    lrow[r] = 0.f;
  }

  // Kh/Kl staging: wave w stages tile rows [w*8, w*8+8) of both arrays;
  // instr i covers 2 rows (1 KB).  Source granule pre-swizzled
  // (16B ^ (row&7)<<4) so linear LDS dest yields the swizzled layout;
  // fragment reads apply the same XOR.
  int koff[4];
#pragma unroll
  for (int i = 0; i < 4; i++) {
    const int r = wave * 8 + i * 2 + (lane >> 5);
    const int cb = ((lane & 31) << 4) ^ ((r & 7) << 4);
    koff[i] = r * 256 + (cb >> 1);
  }
  const int ldsb = wave * 2048;  // elems within one buffer

  // prologue: stage tile 0 into buffer 0
#pragma unroll
  for (int i = 0; i < 4; i++) {
    GLDS16(khp + koff[i], &KhL[0][ldsb + i * 512]);
    GLDS16(klp + koff[i], &KlL[0][ldsb + i * 512]);
  }

  for (int kv0 = 0; kv0 < 2048; kv0 += 64) {
    const int cur = (kv0 >> 6) & 1;
    __syncthreads();  // tile kv0's DMA drained; tile kv0-64 readers done

    // issue next tile's DMA now: a full iteration of cover before its
    // consuming barrier; writes buf[cur^1], whose readers are done (barrier)
    if (kv0 + 64 < 2048) {
      const int kvn = (kv0 + 64) * 256;
#pragma unroll
      for (int i = 0; i < 4; i++) {
        GLDS16(khp + kvn + koff[i], &KhL[cur ^ 1][ldsb + i * 512]);
        GLDS16(klp + kvn + koff[i], &KlL[cur ^ 1][ldsb + i * 512]);
      }
    }

    // S = q_tile @ k_tile^T : 4 subtiles of 16x16, split-bf16 3-pass.
    f32x4 s[4];
#pragma unroll
    for (int j = 0; j < 4; j++) s[j] = zero4;
    __builtin_amdgcn_s_setprio(1);
#pragma unroll
    for (int j = 0; j < 4; j++) {
      const int row = j * 16 + l16;
      const int swz = (row & 7) << 3;  // elem-granularity XOR (16B chunks)
      const int rb = row * 256;
#pragma unroll
      for (int t = 0; t < 8; t++) {
        const int off = rb + ((t * 32 + quad * 8) ^ swz);
        bf16x8 khf = *(const bf16x8*)&KhL[cur][off];
        bf16x8 klf = *(const bf16x8*)&KlL[cur][off];
        s[j] =
            __builtin_amdgcn_mfma_f32_16x16x32_bf16(qhf[t], khf, s[j], 0, 0, 0);
        s[j] =
            __builtin_amdgcn_mfma_f32_16x16x32_bf16(qhf[t], klf, s[j], 0, 0, 0);
        s[j] =
            __builtin_amdgcn_mfma_f32_16x16x32_bf16(qlf[t], khf, s[j], 0, 0, 0);
      }
    }
    __builtin_amdgcn_s_setprio(0);

    // online softmax (rows quad*4+r, cols l16 of 4 kv subtiles)
    float mnew[4], psum[4];
#pragma unroll
    for (int r = 0; r < 4; r++) {
      float mx = fmaxf(fmaxf(s[0][r], s[1][r]), fmaxf(s[2][r], s[3][r]));
#pragma unroll
      for (int off = 1; off < 16; off <<= 1)
        mx = fmaxf(mx, __shfl_xor(mx, off, 16));
      mnew[r] = fmaxf(mrow[r], mx);
      psum[r] = 0.f;
    }
#pragma unroll
    for (int j = 0; j < 4; j++)
#pragma unroll
      for (int r = 0; r < 4; r++) {
        float p = __expf(s[j][r] - mnew[r]);
        s[j][r] = p;
        psum[r] += p;
      }
#pragma unroll
    for (int r = 0; r < 4; r++) {
#pragma unroll
      for (int off = 1; off < 16; off <<= 1)
        psum[r] += __shfl_xor(psum[r], off, 16);
    }
    // defer-max: if no row's max grew, alpha==1 exactly -> skip rescale
    float grow = fmaxf(fmaxf(mnew[0] - mrow[0], mnew[1] - mrow[1]),
                       fmaxf(mnew[2] - mrow[2], mnew[3] - mrow[3]));
    if (__any(grow > 0.f)) {
      float alpha[4];
#pragma unroll
      for (int r = 0; r < 4; r++) {
        alpha[r] = __expf(mrow[r] - mnew[r]);
        lrow[r] = lrow[r] * alpha[r] + psum[r];
        mrow[r] = mnew[r];
      }
#pragma unroll
      for (int dt = 0; dt < 16; dt++) {
        o[dt][0] *= alpha[0];
        o[dt][1] *= alpha[1];
        o[dt][2] *= alpha[2];
        o[dt][3] *= alpha[3];
      }
    } else {
#pragma unroll
      for (int r = 0; r < 4; r++) lrow[r] += psum[r];
    }

    // P: C-layout -> per-wave LDS -> A-operand layout (wave-private)
#pragma unroll
    for (int j = 0; j < 4; j++)
#pragma unroll
      for (int r = 0; r < 4; r++)
        Plds[wave][(quad * 4 + r) * 72 + j * 16 + l16] = (__bf16)s[j][r];
    bf16x8 pa0 = *(const bf16x8*)&Plds[wave][l16 * 72 + quad * 8];
    bf16x8 pa1 = *(const bf16x8*)&Plds[wave][l16 * 72 + 32 + quad * 8];

    // O += P @ V, V fragments JIT from global (L2/L1-resident,
    // compiler-scheduled -- do not hand-pipeline, see R12 post-mortem)
    __builtin_amdgcn_s_setprio(1);
#pragma unroll
    for (int dt = 0; dt < 16; dt++) {
      const __bf16* vr = vp + (size_t)(dt * 16 + l16) * 2048 + kv0 + quad * 8;
      bf16x8 vf0 = *(const bf16x8*)vr;
      bf16x8 vf1 = *(const bf16x8*)(vr + 32);
      o[dt] = __builtin_amdgcn_mfma_f32_16x16x32_bf16(pa0, vf0, o[dt], 0, 0, 0);
      o[dt] = __builtin_amdgcn_mfma_f32_16x16x32_bf16(pa1, vf1, o[dt], 0, 0, 0);
    }
    __builtin_amdgcn_s_setprio(0);
  }

#pragma unroll
  for (int r = 0; r < 4; r++) {
    const float inv = SCALE_INV / lrow[r];
    const int n = qrow + quad * 4 + r;
    const size_t base = ((size_t)bb * 2048 + n) * 2048 + hh * 256;
#pragma unroll
    for (int dt = 0; dt < 16; dt++)
      out[base + dt * 16 + l16] = (__bf16)(o[dt][r] * inv);
  }
}

// Plain bf16 GEMM, C = A[M][K] * Bt[N][K]^T + bias, fp32 store.
__global__ __launch_bounds__(256) void gemm_bt_k(
    const __bf16* __restrict__ A, const __bf16* __restrict__ Bt,
    const float* __restrict__ bias, int M, int Ncols, int K,
    float* __restrict__ outF) {
  __shared__ __bf16 As[128 * 40];
  __shared__ __bf16 Bs[128 * 40];
  const int tid = threadIdx.x, lane = tid & 63, wave = tid >> 6;
  const int l16 = lane & 15, quad = lane >> 4;
  const int wm = (wave >> 1) * 64, wn = (wave & 1) * 64;
  const int m0 = blockIdx.y * 128, n0 = blockIdx.x * 128;
  const int r0 = tid >> 2, kc0 = (tid & 3) * 8;

  f32x4 zero4 = {0.f, 0.f, 0.f, 0.f};
  f32x4 acc[4][4];
#pragma unroll
  for (int i = 0; i < 4; i++)
#pragma unroll
    for (int j = 0; j < 4; j++) acc[i][j] = zero4;

  const __bf16* Aptr = A + (size_t)(m0 + r0) * K + kc0;
  const __bf16* Bptr = Bt + (size_t)(n0 + r0) * K + kc0;
  const size_t rowstep = (size_t)64 * K;

  for (int k0 = 0; k0 < K; k0 += 32) {
    uint4 a0 = *(const uint4*)(Aptr + k0);
    uint4 a1 = *(const uint4*)(Aptr + rowstep + k0);
    uint4 b0 = *(const uint4*)(Bptr + k0);
    uint4 b1 = *(const uint4*)(Bptr + rowstep + k0);
    __syncthreads();
    *(uint4*)&As[r0 * 40 + kc0] = a0;
    *(uint4*)&As[(r0 + 64) * 40 + kc0] = a1;
    *(uint4*)&Bs[r0 * 40 + kc0] = b0;
    *(uint4*)&Bs[(r0 + 64) * 40 + kc0] = b1;
    __syncthreads();
    bf16x8 af[4], bfv[4];
#pragma unroll
    for (int i = 0; i < 4; i++)
      af[i] = *(const bf16x8*)&As[(wm + i * 16 + l16) * 40 + quad * 8];
#pragma unroll
    for (int j = 0; j < 4; j++)
      bfv[j] = *(const bf16x8*)&Bs[(wn + j * 16 + l16) * 40 + quad * 8];
#pragma unroll
    for (int i = 0; i < 4; i++)
#pragma unroll
      for (int j = 0; j < 4; j++)
        acc[i][j] = __builtin_amdgcn_mfma_f32_16x16x32_bf16(af[i], bfv[j],
                                                            acc[i][j], 0, 0, 0);
  }

#pragma unroll
  for (int i = 0; i < 4; i++)
#pragma unroll
    for (int j = 0; j < 4; j++) {
      const int col = n0 + wn + j * 16 + l16;
      const float bv = bias[col];
#pragma unroll
      for (int r = 0; r < 4; r++) {
        const int row = m0 + wm + i * 16 + quad * 4 + r;
        outF[(size_t)row * Ncols + col] = acc[i][j][r] + bv;
      }
    }
}

extern "C" void kernel_launch(void* const* d_in, const int* in_sizes, int n_in,
                              void* d_out, int out_size, void* d_ws,
                              size_t ws_size, hipStream_t stream) {
  const float* x = (const float*)d_in[0];       // [2,2048,2048]
  const float* w_qkv = (const float*)d_in[1];   // [2048,6144]
  const float* b_qkv = (const float*)d_in[2];   // [6144]
  const float* w_proj = (const float*)d_in[3];  // [2048,2048]
  const float* b_proj = (const float*)d_in[4];  // [2048]
  float* out = (float*)d_out;                   // [2,2048,2048] fp32

  const size_t HSZ = (size_t)16 * 2048 * 256;  // 8M elems = 16 MiB bf16
  __bf16* qh = (__bf16*)d_ws;
  __bf16* ql = qh + HSZ;
  __bf16* kh = ql + HSZ;
  __bf16* kl = kh + HSZ;
  __bf16* vT = kl + HSZ;
  __bf16* attn = vT + HSZ;
  __bf16* wprojT = qh;  // aliases qh/ql region AFTER attention

  // Scratch (exact fits): Xh+Xl = 33.55 MB = d_out; per-phase Wh/Wl =
  // 16.78 MB = attn slot.  d_out dead until gemm_bt_k; attn slot dead
  // until attn_fwd_k.
  __bf16* xh = (__bf16*)out;
  __bf16* xl = xh + (size_t)4096 * 2048;
  __bf16* wsp_h = attn;
  __bf16* wsp_l = wsp_h + (size_t)2048 * 2048;

  presplit_x_k<<<dim3(4096), 256, 0, stream>>>(x, xh, xl);
  for (int ph = 0; ph < 3; ph++) {
    transpose_w_split_k<<<dim3(32, 32), 256, 0, stream>>>(w_qkv, wsp_h, wsp_l,
                                                          ph * 2048);
    gemm_qkv_dma_k<<<dim3(16, 32), 256, 0, stream>>>(
        xh, xl, wsp_h, wsp_l, b_qkv, ph * 2048, qh, ql, kh, kl, vT);
  }
  attn_fwd_k<<<dim3(16, 16), 512, 0, stream>>>(qh, ql, kh, kl, vT, attn);
  transpose_cvt_k<<<dim3(64, 64), 256, 0, stream>>>(w_proj, wprojT, 2048, 2048);
  gemm_bt_k<<<dim3(16, 32), 256, 0, stream>>>(attn, wprojT, b_proj, 4096, 2048,
                                              2048, out);
}